// Round 6
// baseline (439.924 us; speedup 1.0000x reference)
//
#include <hip/hip_runtime.h>

// KNN top-16: B=4, N=8192, D=16, k=16, fp32 in, int32 index out.
// FROZEN key model (validated R11-R24, absmax=0): harness np twin =
//   dot  = BLAS microkernel single-accumulator FMA chain, k = 0..15
//   norm = numpy AVX512 pairwise tree: r_j=m_j+m_{j+8}; q_j=r_j+r_{j+4};
//          fl(fl(q0+q2)+fl(q1+q3))
//   val  = fl( fl(ni + fl(-2*dot)) + nj ), ties -> lower index
//   pk_* VOP3P per-half == scalar IEEE (validated R23/R24, absmax=0)
// Keys packed u64 = (mono32(key)<<32)|idx: u64 asc == (key asc, idx asc).
// R25: 4 blocks/CU via query-split. Evidence: R23 (-25% VALU, flat),
// R24 (-50% LDS reads, same VALU, waves 16->8, +20% time) => sequencer
// gap-limited: per-wave stalls (ds_read latency -> 16-deep FMA chain ->
// push -> __any) only hidden by co-resident waves. Double waves 16->32:
// 32 queries/block (grid 1024 = 4 blocks/CU); lane-half h processes
// pairs {h, h+2} per chunk (union = full segment; 16 streams/query,
// 16-way tournament merge, 2 passes x 16 queries, overlay 32KB at base).
// Fit: CAP 7 -> pbuf 28KB, LDS 37.4KB <= 40KB; launch_bounds(512,4) ->
// VGPR cap 64 (R23 natural = 64). Branchless push (uncond write, cond
// count advance) drops exec-mask juggling. Predict: occ 40->~78, VGPR
// 64, WRITE_SIZE ~2MB (balloon => spilled => revert to (512,3)),
// dur 367->280-310 if wave-starved; flat+no-spill => issue-floor next.

#define B_    4
#define N_    8192
#define D_    16
#define K_    16
#define SEGS_ 8
#define SEG_  (N_ / SEGS_)   // 1024
#define CH_   8              // rows per staged chunk
#define NCH_  (SEG_ / CH_)   // 128 chunks
#define BT_   512            // 8 waves
#define CAP_  7              // per-lane LDS push-buffer capacity
#define NQ_   (B_ * N_)      // 32768 queries
#define QB_   32             // queries per block

typedef unsigned long long u64;
typedef float v2f __attribute__((ext_vector_type(2)));

// VOP3P packed fp32: one issue slot, two IEEE fp32 ops (per-half == scalar)
__device__ __forceinline__ v2f pk_fma(v2f a, v2f b, v2f c) {
  v2f d;
  asm("v_pk_fma_f32 %0, %1, %2, %3" : "=v"(d) : "v"(a), "v"(b), "v"(c));
  return d;
}
__device__ __forceinline__ v2f pk_mul(v2f a, v2f b) {
  v2f d;
  asm("v_pk_mul_f32 %0, %1, %2" : "=v"(d) : "v"(a), "v"(b));
  return d;
}
__device__ __forceinline__ v2f pk_add(v2f a, v2f b) {
  v2f d;
  asm("v_pk_add_f32 %0, %1, %2" : "=v"(d) : "v"(a), "v"(b));
  return d;
}

// numpy AVX512 pairwise-sum tree for 16 contiguous floats. FROZEN.
__device__ __forceinline__ float np_norm16(const float* __restrict__ p) {
#pragma clang fp contract(off)
  float m[16];
#pragma unroll
  for (int d = 0; d < 16; ++d) m[d] = p[d] * p[d];
  float r[8];
#pragma unroll
  for (int j = 0; j < 8; ++j) r[j] = m[j] + m[j + 8];
  float q[4];
#pragma unroll
  for (int j = 0; j < 4; ++j) q[j] = r[j] + r[j + 4];
  return (q[0] + q[2]) + (q[1] + q[3]);
}

// monotone fp32->u32: uint ascending == float ascending (handles negatives)
__device__ __forceinline__ unsigned mono32(float f) {
  unsigned u = __float_as_uint(f);
  return u ^ ((unsigned)((int)u >> 31) | 0x80000000u);
}

__global__ __launch_bounds__(256) void knn_norms(const float* __restrict__ x,
                                                 float* __restrict__ nrm) {
  int q = blockIdx.x * 256 + threadIdx.x;
  float row[16];
  const float4* xv = (const float4*)(x + (size_t)q * D_);
  float4 a = xv[0], b = xv[1], c = xv[2], d = xv[3];
  row[0]=a.x; row[1]=a.y; row[2]=a.z; row[3]=a.w;
  row[4]=b.x; row[5]=b.y; row[6]=b.z; row[7]=b.w;
  row[8]=c.x; row[9]=c.y; row[10]=c.z; row[11]=c.w;
  row[12]=d.x; row[13]=d.y; row[14]=d.z; row[15]=d.w;
  nrm[q] = np_norm16(row);
}

// ascending insert; '>' keeps earlier (lower idx) on ties
__device__ __forceinline__ void insert16(float d, int j, float (&kd)[K_], int (&ki)[K_]) {
  float cd = d; int ci = j;
#pragma unroll
  for (int p = 0; p < K_; ++p) {
    bool gt = kd[p] > cd;
    float t0 = gt ? cd : kd[p];
    float t1 = gt ? kd[p] : cd;
    int   t2 = gt ? ci : ki[p];
    int   t3 = gt ? ki[p] : ci;
    kd[p] = t0; cd = t1; ki[p] = t2; ci = t3;
  }
}

__device__ __forceinline__ void flushbuf(u64* __restrict__ pbuf, int tid,
                                         int& count, float& thr,
                                         float (&kd)[K_], int (&ki)[K_]) {
#pragma unroll 1
  for (int s = 0; s < CAP_; ++s) {
    if (s < count) {
      u64 e = pbuf[s * BT_ + tid];
      float d = __uint_as_float((unsigned)(e >> 32));
      if (d < thr) {
        int j = (int)(e & 0xffffu);
        insert16(d, j, kd, ki);
        thr = kd[K_ - 1];
      }
    }
  }
  count = 0;
}

__global__ __launch_bounds__(BT_, 4) void knn_fused(const float* __restrict__ x,
                                                    const float* __restrict__ nrm,
                                                    int* __restrict__ out) {
  __shared__ u64 smem[4672];                       // 37.4 KB -> 4 blocks/CU
  v2f*    stageT = (v2f*)smem;                     // [(w*2+b)*64 + p*16+d], 8 KB
  float*  stageN = (float*)(smem + 1024);          // [(w*2+b)*8 + i], 512 B
  u64*    pbuf   = smem + 1088;                    // [s*512 + tid], 28 KB
  // merge overlay (after final flush + barrier): smem[0], 16*16*16*8 = 32 KB

  const int tid  = threadIdx.x;
  const int w    = tid >> 6;                       // wave id = segment
  const int lane = tid & 63;
  const int h    = lane >> 5;                      // candidate-half (pair parity)
  const int ql   = lane & 31;                      // query-local id
  const int q    = blockIdx.x * QB_ + ql;          // global query
  const int bq   = (int)((blockIdx.x * (unsigned)QB_) >> 13);  // batch
  const int row0 = bq * N_ + w * SEG_;
  const float* __restrict__ cbase = x + (size_t)row0 * D_;
  const float* __restrict__ nbase = nrm + row0;

  const int p_ = lane >> 4;                        // staging pair slot 0..3
  const int d_ = lane & 15;                        // staging dim 0..15

  // packed query: qq[d] = (qa[d], qa[d])
  v2f qq[D_];
  {
    const float4* qv = (const float4*)(x + (size_t)q * D_);
    float4 v0 = qv[0], v1 = qv[1], v2 = qv[2], v3 = qv[3];
    qq[0]=(v2f){v0.x,v0.x}; qq[1]=(v2f){v0.y,v0.y}; qq[2]=(v2f){v0.z,v0.z}; qq[3]=(v2f){v0.w,v0.w};
    qq[4]=(v2f){v1.x,v1.x}; qq[5]=(v2f){v1.y,v1.y}; qq[6]=(v2f){v1.z,v1.z}; qq[7]=(v2f){v1.w,v1.w};
    qq[8]=(v2f){v2.x,v2.x}; qq[9]=(v2f){v2.y,v2.y}; qq[10]=(v2f){v2.z,v2.z}; qq[11]=(v2f){v2.w,v2.w};
    qq[12]=(v2f){v3.x,v3.x}; qq[13]=(v2f){v3.y,v3.y}; qq[14]=(v2f){v3.z,v3.z}; qq[15]=(v2f){v3.w,v3.w};
  }
  const float ni = nrm[q];
  const v2f nip = (v2f){ni, ni};
  const v2f m2  = (v2f){-2.0f, -2.0f};

  float kd[K_]; int ki[K_];
#pragma unroll
  for (int p = 0; p < K_; ++p) { kd[p] = 3.4e38f; ki[p] = 0; }
  float thr = 3.4e38f;
  int count = 0;

  // stage chunk 0 pair-transposed (per-wave-private LDS; wave-synchronous)
  {
    float g0 = cbase[(2 * p_) * D_ + d_];
    float g1 = cbase[(2 * p_ + 1) * D_ + d_];
    stageT[(w * 2 + 0) * 64 + p_ * 16 + d_] = (v2f){g0, g1};
    if (lane < CH_) stageN[(w * 2 + 0) * CH_ + lane] = nbase[lane];
  }

#pragma unroll 1
  for (int c = 0; c < NCH_; ++c) {
    const int b = c & 1;
    // prefetch chunk c+1 into registers (overlaps compute below)
    float pg0 = 0.f, pg1 = 0.f, pn = 0.f;
    const bool more = (c + 1 < NCH_);
    if (more) {
      const float* cb = cbase + (size_t)(c + 1) * CH_ * D_;
      pg0 = cb[(2 * p_) * D_ + d_];
      pg1 = cb[(2 * p_ + 1) * D_ + d_];
      if (lane < CH_) pn = nbase[(c + 1) * CH_ + lane];
    }

    const float4* tp = (const float4*)(stageT + (w * 2 + b) * 64);
    const float*  nW = stageN + (w * 2 + b) * CH_;
    const int j0 = c * CH_;

#pragma unroll 1
    for (int t = 0; t < 2; ++t) {
      const int pr = 2 * t + h;                    // this lane's pair in chunk
      // 8 per-lane-half b128 reads: f_i = (c0[2i], c1[2i], c0[2i+1], c1[2i+1])
      float4 f0 = tp[pr*8+0], f1 = tp[pr*8+1], f2 = tp[pr*8+2], f3 = tp[pr*8+3];
      float4 f4 = tp[pr*8+4], f5 = tp[pr*8+5], f6 = tp[pr*8+6], f7 = tp[pr*8+7];

      // frozen single-accumulator chain; lo=cand0 / hi=cand1
      v2f acc = (v2f){0.f, 0.f};
      acc = pk_fma(qq[0],  (v2f){f0.x, f0.y}, acc);
      acc = pk_fma(qq[1],  (v2f){f0.z, f0.w}, acc);
      acc = pk_fma(qq[2],  (v2f){f1.x, f1.y}, acc);
      acc = pk_fma(qq[3],  (v2f){f1.z, f1.w}, acc);
      acc = pk_fma(qq[4],  (v2f){f2.x, f2.y}, acc);
      acc = pk_fma(qq[5],  (v2f){f2.z, f2.w}, acc);
      acc = pk_fma(qq[6],  (v2f){f3.x, f3.y}, acc);
      acc = pk_fma(qq[7],  (v2f){f3.z, f3.w}, acc);
      acc = pk_fma(qq[8],  (v2f){f4.x, f4.y}, acc);
      acc = pk_fma(qq[9],  (v2f){f4.z, f4.w}, acc);
      acc = pk_fma(qq[10], (v2f){f5.x, f5.y}, acc);
      acc = pk_fma(qq[11], (v2f){f5.z, f5.w}, acc);
      acc = pk_fma(qq[12], (v2f){f6.x, f6.y}, acc);
      acc = pk_fma(qq[13], (v2f){f6.z, f6.w}, acc);
      acc = pk_fma(qq[14], (v2f){f7.x, f7.y}, acc);
      acc = pk_fma(qq[15], (v2f){f7.z, f7.w}, acc);

      // val = fl( fl(ni + fl(-2*dot)) + nj ), per half (pk ops = scalar IEEE)
      v2f njp = *(const v2f*)(nW + 2 * pr);
      v2f ii  = pk_mul(m2, acc);
      v2f uu  = pk_add(nip, ii);
      v2f dd  = pk_add(uu, njp);
      const int j = j0 + 2 * pr;

      // branchless push: unconditional write to slot `count`, cond. advance
      pbuf[count * BT_ + tid] =
          ((u64)__float_as_uint(dd.x) << 32) | (unsigned)j;
      count += (dd.x < thr) ? 1 : 0;
      pbuf[count * BT_ + tid] =
          ((u64)__float_as_uint(dd.y) << 32) | (unsigned)(j + 1);
      count += (dd.y < thr) ? 1 : 0;

      if (__any(count >= CAP_ - 1)) flushbuf(pbuf, tid, count, thr, kd, ki);
    }

    // write prefetched chunk into the other buffer (pair-transposed)
    if (more) {
      stageT[(w * 2 + (b ^ 1)) * 64 + p_ * 16 + d_] = (v2f){pg0, pg1};
      if (lane < CH_) stageN[(w * 2 + (b ^ 1)) * CH_ + lane] = pn;
    }
  }
  flushbuf(pbuf, tid, count, thr, kd, ki);

  // ---- publish + 16-way merge: 16 streams/query (8 segs x 2 halves), ----
  // ---- 2 passes x 16 queries, 32 KB overlay at smem base.            ----
  u64* mrg = smem;
  const int strm = w * 2 + h;                      // my stream id 0..15
  __syncthreads();   // all waves done with stage/push regions before overlay
#pragma unroll 1
  for (int P = 0; P < 2; ++P) {
    if ((ql >> 4) == P) {
      const int m = ql & 15;
#pragma unroll
      for (int p = 0; p < K_; ++p) {
        mrg[((size_t)strm * 16 + p) * 16 + m] =
            ((u64)mono32(kd[p]) << 32) | (unsigned)(w * SEG_ + ki[p]);
      }
    }
    __syncthreads();

    // merge: 16 lanes per query; 16 queries -> tid<256 (waves 0..3).
    if (tid < 256) {
      const int m = tid >> 4;                      // query-in-pass
      const int s = tid & 15;                      // my stream
      int ptr = 0;
#pragma unroll 1
      for (int r = 0; r < K_; ++r) {
        u64 hd = mrg[((size_t)s * 16 + ptr) * 16 + m];
        u64 mv = hd, o;
        o = __shfl_xor(mv, 1); mv = (o < mv) ? o : mv;
        o = __shfl_xor(mv, 2); mv = (o < mv) ? o : mv;
        o = __shfl_xor(mv, 4); mv = (o < mv) ? o : mv;
        o = __shfl_xor(mv, 8); mv = (o < mv) ? o : mv;
        if (hd == mv) ++ptr;                       // exactly one lane advances
        if (s == 0)
          out[(size_t)(blockIdx.x * QB_ + P * 16 + m) * K_ + r] =
              (int)(mv & 0xffffu);
      }
    }
    __syncthreads();                               // overlay reuse by pass 2
  }
}

extern "C" void kernel_launch(void* const* d_in, const int* in_sizes, int n_in,
                              void* d_out, int out_size, void* d_ws, size_t ws_size,
                              hipStream_t stream) {
  const float* x = (const float*)d_in[0];
  float* nrm = (float*)d_ws;                       // 128 KB of workspace
  int* out = (int*)d_out;

  knn_norms<<<NQ_ / 256, 256, 0, stream>>>(x, nrm);
  knn_fused<<<NQ_ / QB_, BT_, 0, stream>>>(x, nrm, out);
}